// Round 3
// baseline (157.387 us; speedup 1.0000x reference)
//
#include <hip/hip_runtime.h>
#include <math.h>

#define SIMG 128
#define NPIX (SIMG*SIMG)
#define MAXCHUNK 20
#define BATCH 250   // faces staged in LDS per sub-batch: 250*20 floats = 20 KB

// ((a0*b0 + a1*b1) + a2*b2) with strict per-op fp32 rounding (matches numpy einsum order)
__device__ __forceinline__ float dot3_rn(float a0,float a1,float a2,float b0,float b1,float b2){
  return __fadd_rn(__fadd_rn(__fmul_rn(a0,b0),__fmul_rn(a1,b1)),__fmul_rn(a2,b2));
}

// Compute one face record (20 floats) with the exact reference op sequence.
// [0..3] bbox(+-1e-4), [4..9] x0,y0,x1,y1,x2,y2, [10..12] z0,z1,z2,
// [13..18] e0x,e0y,e1x,e1y,e2x,e2y, [19] pad
__device__ __forceinline__ void face_record(
    const float* __restrict__ verts, const int* __restrict__ faces,
    const float* __restrict__ Rm, const float* __restrict__ tv,
    const float* __restrict__ Km, int f, float* r)
{
  float uu[3], vv2[3], zz[3];
  #pragma unroll
  for (int k=0;k<3;k++){
    int vi = faces[3*f+k];
    float X = verts[3*vi+0], Y = verts[3*vi+1], Z = verts[3*vi+2];
    float cx = __fadd_rn(dot3_rn(X,Y,Z, Rm[0],Rm[1],Rm[2]), tv[0]);
    float cy = __fadd_rn(dot3_rn(X,Y,Z, Rm[3],Rm[4],Rm[5]), tv[1]);
    float cz = __fadd_rn(dot3_rn(X,Y,Z, Rm[6],Rm[7],Rm[8]), tv[2]);
    float zd = __fadd_rn(cz, 1e-9f);
    float x_ = __fdiv_rn(cx, zd);
    float y_ = __fdiv_rn(cy, zd);
    float ur = __fadd_rn(__fadd_rn(__fmul_rn(x_,Km[0]),__fmul_rn(y_,Km[1])), Km[2]);
    float vr = __fadd_rn(__fadd_rn(__fmul_rn(x_,Km[3]),__fmul_rn(y_,Km[4])), Km[5]);
    float vflip = __fsub_rn(128.0f, vr);
    uu[k]  = __fdiv_rn(__fmul_rn(2.0f, __fsub_rn(ur,   64.0f)), 128.0f);
    vv2[k] = __fdiv_rn(__fmul_rn(2.0f, __fsub_rn(vflip,64.0f)), 128.0f);
    zz[k]  = cz;
  }
  float x0=uu[0], y0=vv2[0], x1=uu[1], y1=vv2[1], x2=uu[2], y2=vv2[2];
  float e0x=__fsub_rn(x2,x1), e0y=__fsub_rn(y2,y1);
  float e1x=__fsub_rn(x0,x2), e1y=__fsub_rn(y0,y2);
  float e2x=__fsub_rn(x1,x0), e2y=__fsub_rn(y1,y0);
  r[0]=fminf(fminf(x0,x1),x2) - 1e-4f;
  r[1]=fmaxf(fmaxf(x0,x1),x2) + 1e-4f;
  r[2]=fminf(fminf(y0,y1),y2) - 1e-4f;
  r[3]=fmaxf(fmaxf(y0,y1),y2) + 1e-4f;
  r[4]=x0; r[5]=y0; r[6]=x1; r[7]=y1;
  r[8]=x2; r[9]=y2; r[10]=zz[0]; r[11]=zz[1];
  r[12]=zz[2]; r[13]=e0x; r[14]=e0y; r[15]=e1x;
  r[16]=e1y; r[17]=e2x; r[18]=e2y; r[19]=0.0f;
}

// grid (64 tiles, nchunk); block 256 (1 pixel each). Face records built in LDS by
// this block (redundant per tile, but tiny), then broadcast-read in the pixel loop.
__global__ void __launch_bounds__(256) k_raster(
    const float* __restrict__ verts, const int* __restrict__ faces,
    const float* __restrict__ Rm, const float* __restrict__ tv,
    const float* __restrict__ Km,
    float* __restrict__ pd, int* __restrict__ pi,
    int* __restrict__ counter, int* __restrict__ gmax_i,
    int F, int CF)
{
  __shared__ __align__(16) float sf[BATCH*20];
  int tile  = blockIdx.x;
  int chunk = blockIdx.y;
  // init cross-kernel sync vars (visible to k_resolve_loss via stream order)
  if (tile==0 && chunk==0 && threadIdx.x==0) { *counter = 0; *gmax_i = (int)0x80000000; }

  int tx = threadIdx.x & 15, ty = threadIdx.x >> 4;
  int x = ((tile & 7) << 4) + tx;
  int y = ((tile >> 3) << 4) + ty;
  float px = (float)(2*x + 1 - SIMG) / 128.0f;   // exact
  float py = (float)(2*y + 1 - SIMG) / 128.0f;   // exact
  int bx0 = (tile & 7) << 4, by0 = (tile >> 3) << 4;
  float tpx0 = (float)(2*bx0      + 1 - SIMG) / 128.0f;
  float tpx1 = (float)(2*(bx0+15) + 1 - SIMG) / 128.0f;
  float tpy0 = (float)(2*by0      + 1 - SIMG) / 128.0f;
  float tpy1 = (float)(2*(by0+15) + 1 - SIMG) / 128.0f;

  int f0 = chunk*CF;
  int f1 = min(F, f0 + CF);
  float bestd = __builtin_inff();
  int   besti = 0;
  for (int base = f0; base < f1; base += BATCH) {
    int nb = min(BATCH, f1 - base);
    __syncthreads();   // protect LDS reuse across batches
    if ((int)threadIdx.x < nb)
      face_record(verts, faces, Rm, tv, Km, base + (int)threadIdx.x,
                  sf + (size_t)threadIdx.x*20);
    __syncthreads();
    for (int j = 0; j < nb; ++j) {
      const float4* rp = (const float4*)(sf + (size_t)j*20);
      float4 r0 = rp[0];   // bbox; broadcast LDS read (block-uniform branch)
      if (r0.y < tpx0 || r0.x > tpx1 || r0.w < tpy0 || r0.z > tpy1) continue;
      float4 r1 = rp[1], r2 = rp[2], r3 = rp[3], r4 = rp[4];
      float x0=r1.x, y0=r1.y, x1=r1.z, y1=r1.w;
      float x2=r2.x, y2=r2.y, z0=r2.z, z1=r2.w;
      float z2=r3.x, e0x=r3.y, e0y=r3.z, e1x=r3.w;
      float e1y=r4.x, e2x=r4.y, e2y=r4.z;
      // w = ex*(py-ay) - ey*(px-ax), strict per-op rounding (no FMA)
      float w0 = __fsub_rn(__fmul_rn(e0x,__fsub_rn(py,y1)), __fmul_rn(e0y,__fsub_rn(px,x1)));
      float w1 = __fsub_rn(__fmul_rn(e1x,__fsub_rn(py,y2)), __fmul_rn(e1y,__fsub_rn(px,x2)));
      float w2 = __fsub_rn(__fmul_rn(e2x,__fsub_rn(py,y0)), __fmul_rn(e2y,__fsub_rn(px,x0)));
      float area = __fadd_rn(__fadd_rn(w0,w1),w2);
      bool sgn = (w0>=0.0f && w1>=0.0f && w2>=0.0f) || (w0<=0.0f && w1<=0.0f && w2<=0.0f);
      bool okf = fabsf(area) > 1e-10f;
      if (sgn && okf) {
        float inv = __fdiv_rn(1.0f, area);
        float q0 = __fdiv_rn(__fmul_rn(w0,inv), z0);
        float q1 = __fdiv_rn(__fmul_rn(w1,inv), z1);
        float q2 = __fdiv_rn(__fmul_rn(w2,inv), z2);
        float den = __fadd_rn(__fadd_rn(__fadd_rn(q0,q1),q2), 1e-12f);
        float zp = __fdiv_rn(1.0f, den);
        if (zp > 0.1f && zp < 100.0f && zp < bestd) { bestd = zp; besti = base + j; }
      }
    }
  }
  int pix = y*SIMG + x;
  pd[(size_t)chunk*NPIX + pix] = bestd;
  pi[(size_t)chunk*NPIX + pix] = besti;
}

// grid 64 x 256: combine chunks (in face order -> argmin first-index semantics),
// compute winner color from raw vertices (exact ref op sequence), write rgb+gray,
// block max -> atomicMax, last block computes the loss.
__global__ void __launch_bounds__(256) k_resolve_loss(
    const float* __restrict__ pd, const int* __restrict__ pi,
    const float* __restrict__ verts, const int* __restrict__ faces,
    const float* __restrict__ tex,
    const float* __restrict__ ldir, const float* __restrict__ idir,
    const float* __restrict__ iamb,
    const float* __restrict__ mimg, const float* __restrict__ mask,
    float* __restrict__ out_rgb, float* __restrict__ gray,
    int* __restrict__ counter, int* __restrict__ gmax_i,
    float* __restrict__ out, int nchunk)
{
  int pix = blockIdx.x*blockDim.x + threadIdx.x;
  float bestd = __builtin_inff();
  int   besti = 0;
  for (int c = 0; c < nchunk; ++c) {
    float d = pd[(size_t)c*NPIX + pix];
    int   i = pi[(size_t)c*NPIX + pix];
    if (d < bestd) { bestd = d; besti = i; }
  }
  bool hit = bestd < 1e30f;
  float c0=0.0f, c1=0.0f, c2=0.0f;
  if (hit) {
    int w = besti;
    int i0 = faces[3*w+0], i1 = faces[3*w+1], i2 = faces[3*w+2];
    float p0x=verts[3*i0+0], p0y=verts[3*i0+1], p0z=verts[3*i0+2];
    float p1x=verts[3*i1+0], p1y=verts[3*i1+1], p1z=verts[3*i1+2];
    float p2x=verts[3*i2+0], p2y=verts[3*i2+1], p2z=verts[3*i2+2];
    float ax=__fsub_rn(p0x,p1x), ay=__fsub_rn(p0y,p1y), az=__fsub_rn(p0z,p1z);
    float bx=__fsub_rn(p2x,p1x), by=__fsub_rn(p2y,p1y), bz=__fsub_rn(p2z,p1z);
    float nx=__fsub_rn(__fmul_rn(ay,bz),__fmul_rn(az,by));
    float ny=__fsub_rn(__fmul_rn(az,bx),__fmul_rn(ax,bz));
    float nz=__fsub_rn(__fmul_rn(ax,by),__fmul_rn(ay,bx));
    float nn=__fsqrt_rn(dot3_rn(nx,ny,nz,nx,ny,nz));
    nn = fmaxf(nn, 1e-5f);
    nx=__fdiv_rn(nx,nn); ny=__fdiv_rn(ny,nn); nz=__fdiv_rn(nz,nn);
    float cosv = fmaxf(0.0f, dot3_rn(nx,ny,nz, ldir[0],ldir[1],ldir[2]));
    float light = __fadd_rn(iamb[0], __fmul_rn(idir[0], cosv));
    c0 = __fmul_rn(tex[3*w+0], light);
    c1 = __fmul_rn(tex[3*w+1], light);
    c2 = __fmul_rn(tex[3*w+2], light);
  }
  out_rgb[pix]          = c0;
  out_rgb[NPIX + pix]   = c1;
  out_rgb[2*NPIX + pix] = c2;
  float g = __fadd_rn(__fadd_rn(c0,c1),c2);
  // publish gray with agent-scope store (bypasses L1; coherent across XCD L2s)
  __hip_atomic_store(&gray[pix], g, __ATOMIC_RELAXED, __HIP_MEMORY_SCOPE_AGENT);

  // block max -> device atomicMax (nonneg floats: int compare is monotone)
  float m = g;
  #pragma unroll
  for (int off = 32; off > 0; off >>= 1) m = fmaxf(m, __shfl_down(m, off, 64));
  __shared__ float sm[4];
  if ((threadIdx.x & 63) == 0) sm[threadIdx.x >> 6] = m;
  __syncthreads();
  if (threadIdx.x == 0) {
    m = fmaxf(fmaxf(sm[0],sm[1]), fmaxf(sm[2],sm[3]));
    atomicMax(gmax_i, __float_as_int(m));
  }

  // last-block-does-the-loss
  __shared__ int is_last;
  __threadfence();   // release: make gray/gmax visible at agent scope
  if (threadIdx.x == 0) {
    int p = atomicAdd(counter, 1);
    is_last = (p == (int)gridDim.x - 1);
  }
  __syncthreads();
  if (!is_last) return;
  __threadfence();   // acquire: see other blocks' gray + gmax

  float mx = __int_as_float(__hip_atomic_load(gmax_i, __ATOMIC_RELAXED, __HIP_MEMORY_SCOPE_AGENT));
  float ssum = 0.0f, msum = 0.0f;
  for (int j = 0; j < NPIX/256; ++j) {
    int p2 = j*256 + threadIdx.x;
    float gv = __hip_atomic_load(&gray[p2], __ATOMIC_RELAXED, __HIP_MEMORY_SCOPE_AGENT);
    float gg = __fdiv_rn(gv, mx);
    float d  = __fsub_rn(gg, mimg[p2]);
    ssum = __fadd_rn(ssum, __fmul_rn(d,d));
    msum = __fadd_rn(msum, mask[p2]);
  }
  #pragma unroll
  for (int off = 32; off > 0; off >>= 1) {
    ssum += __shfl_down(ssum, off, 64);
    msum += __shfl_down(msum, off, 64);
  }
  __shared__ float s1[4], s2[4];
  if ((threadIdx.x & 63) == 0) { s1[threadIdx.x>>6] = ssum; s2[threadIdx.x>>6] = msum; }
  __syncthreads();
  if (threadIdx.x == 0) {
    ssum = ((s1[0]+s1[1])+(s1[2]+s1[3]));
    msum = ((s2[0]+s2[1])+(s2[2]+s2[3]));
    out[0] = __fdiv_rn(ssum, msum);
  }
}

extern "C" void kernel_launch(void* const* d_in, const int* in_sizes, int n_in,
                              void* d_out, int out_size, void* d_ws, size_t ws_size,
                              hipStream_t stream)
{
  const float* verts = (const float*)d_in[0];
  const int*   faces = (const int*)  d_in[1];
  const float* tex   = (const float*)d_in[2];
  const float* Rm    = (const float*)d_in[3];
  const float* tv    = (const float*)d_in[4];
  const float* Km    = (const float*)d_in[5];
  const float* mimg  = (const float*)d_in[6];
  const float* mask  = (const float*)d_in[7];
  const float* ldir  = (const float*)d_in[8];
  const float* idir  = (const float*)d_in[9];
  const float* iamb  = (const float*)d_in[10];
  int F = in_sizes[1] / 3;

  // ws layout (floats): gray NPIX | gmax,counter (+pad to 64) | pd nchunk*NPIX | pi nchunk*NPIX
  size_t fixed_floats = (size_t)NPIX + 64;
  size_t avail_floats = ws_size / 4;
  int nchunk = 1;
  if (avail_floats > fixed_floats) {
    size_t per_chunk = (size_t)NPIX * 2;
    size_t c = (avail_floats - fixed_floats) / per_chunk;
    nchunk = (int)(c < 1 ? 1 : (c > MAXCHUNK ? MAXCHUNK : c));
  }
  int CF = (F + nchunk - 1) / nchunk;

  float* ws      = (float*)d_ws;
  float* gray    = ws;                                  // NPIX
  int*   gmax_i  = (int*)(ws + NPIX);                   // 1
  int*   counter = gmax_i + 1;                          // 1 (+62 pad)
  float* pd      = ws + NPIX + 64;                      // nchunk*NPIX
  int*   pi      = (int*)(pd + (size_t)nchunk*NPIX);    // nchunk*NPIX
  float* out     = (float*)d_out;

  hipLaunchKernelGGL(k_raster, dim3(64, nchunk), dim3(256), 0, stream,
                     verts, faces, Rm, tv, Km, pd, pi, counter, gmax_i, F, CF);
  hipLaunchKernelGGL(k_resolve_loss, dim3(64), dim3(256), 0, stream,
                     pd, pi, verts, faces, tex, ldir, idir, iamb, mimg, mask,
                     out + 1, gray, counter, gmax_i, out, nchunk);
}

// Round 4
// 152.867 us; speedup vs baseline: 1.0296x; 1.0296x over previous
//
#include <hip/hip_runtime.h>
#include <math.h>

#define SIMG 128
#define NPIX (SIMG*SIMG)
#define MAXCHUNK 20
#define BATCH 256

// ((a0*b0 + a1*b1) + a2*b2) with strict per-op fp32 rounding (matches numpy einsum order)
__device__ __forceinline__ float dot3_rn(float a0,float a1,float a2,float b0,float b1,float b2){
  return __fadd_rn(__fadd_rn(__fmul_rn(a0,b0),__fmul_rn(a1,b1)),__fmul_rn(a2,b2));
}

// Per-face record: 20 floats (80 B, 16B-aligned):
// [0..3] bbox(+-1e-4)  [4..9] x0,y0,x1,y1,x2,y2  [10..12] z0,z1,z2
// [13..18] e0x,e0y,e1x,e1y,e2x,e2y  [19] pad
// Exact reference op sequence (validated absmax=0 in R2/R3 — do not reorder).
__global__ void k_setup(const float* __restrict__ verts, const int* __restrict__ faces,
                        const float* __restrict__ Rm, const float* __restrict__ tv,
                        const float* __restrict__ Km,
                        float* __restrict__ frec,
                        int* __restrict__ counter, int* __restrict__ gmax_i, int F)
{
  int f = blockIdx.x*blockDim.x + threadIdx.x;
  if (f == 0) { *counter = 0; *gmax_i = (int)0x80000000; }
  if (f >= F) return;
  float uu[3], vv2[3], zz[3];
  #pragma unroll
  for (int k=0;k<3;k++){
    int vi = faces[3*f+k];
    float X = verts[3*vi+0], Y = verts[3*vi+1], Z = verts[3*vi+2];
    float cx = __fadd_rn(dot3_rn(X,Y,Z, Rm[0],Rm[1],Rm[2]), tv[0]);
    float cy = __fadd_rn(dot3_rn(X,Y,Z, Rm[3],Rm[4],Rm[5]), tv[1]);
    float cz = __fadd_rn(dot3_rn(X,Y,Z, Rm[6],Rm[7],Rm[8]), tv[2]);
    float zd = __fadd_rn(cz, 1e-9f);
    float x_ = __fdiv_rn(cx, zd);
    float y_ = __fdiv_rn(cy, zd);
    float ur = __fadd_rn(__fadd_rn(__fmul_rn(x_,Km[0]),__fmul_rn(y_,Km[1])), Km[2]);
    float vr = __fadd_rn(__fadd_rn(__fmul_rn(x_,Km[3]),__fmul_rn(y_,Km[4])), Km[5]);
    float vflip = __fsub_rn(128.0f, vr);
    uu[k]  = __fdiv_rn(__fmul_rn(2.0f, __fsub_rn(ur,   64.0f)), 128.0f);
    vv2[k] = __fdiv_rn(__fmul_rn(2.0f, __fsub_rn(vflip,64.0f)), 128.0f);
    zz[k]  = cz;
  }
  float x0=uu[0], y0=vv2[0], x1=uu[1], y1=vv2[1], x2=uu[2], y2=vv2[2];
  float e0x=__fsub_rn(x2,x1), e0y=__fsub_rn(y2,y1);
  float e1x=__fsub_rn(x0,x2), e1y=__fsub_rn(y0,y2);
  float e2x=__fsub_rn(x1,x0), e2y=__fsub_rn(y1,y0);
  float* r = frec + (size_t)f*20;
  r[0]=fminf(fminf(x0,x1),x2) - 1e-4f;
  r[1]=fmaxf(fmaxf(x0,x1),x2) + 1e-4f;
  r[2]=fminf(fminf(y0,y1),y2) - 1e-4f;
  r[3]=fmaxf(fmaxf(y0,y1),y2) + 1e-4f;
  r[4]=x0; r[5]=y0; r[6]=x1; r[7]=y1;
  r[8]=x2; r[9]=y2; r[10]=zz[0]; r[11]=zz[1];
  r[12]=zz[2]; r[13]=e0x; r[14]=e0y; r[15]=e1x;
  r[16]=e1y; r[17]=e2x; r[18]=e2y; r[19]=0.0f;
}

// grid (64 tiles, nchunk); block 256 (1 pixel each).
// Phase 1: parallel bbox test + order-preserving ballot compaction -> slist.
// Phase 2: straight-line survivor loop, A/B register prefetch (global vector loads).
__global__ void __launch_bounds__(256) k_raster(
    const float* __restrict__ frec,
    float* __restrict__ pd, int* __restrict__ pi, int F, int CF)
{
  __shared__ unsigned long long smask[4];
  __shared__ int slist[BATCH];
  __shared__ int s_ns;
  int tile  = blockIdx.x;
  int chunk = blockIdx.y;
  int tx = threadIdx.x & 15, ty = threadIdx.x >> 4;
  int x = ((tile & 7) << 4) + tx;
  int y = ((tile >> 3) << 4) + ty;
  float px = (float)(2*x + 1 - SIMG) / 128.0f;   // exact
  float py = (float)(2*y + 1 - SIMG) / 128.0f;   // exact
  int bx0 = (tile & 7) << 4, by0 = (tile >> 3) << 4;
  float tpx0 = (float)(2*bx0      + 1 - SIMG) / 128.0f;
  float tpx1 = (float)(2*(bx0+15) + 1 - SIMG) / 128.0f;
  float tpy0 = (float)(2*by0      + 1 - SIMG) / 128.0f;
  float tpy1 = (float)(2*(by0+15) + 1 - SIMG) / 128.0f;

  int f0 = chunk*CF;
  int f1 = min(F, f0 + CF);
  float bestd = __builtin_inff();
  int   besti = 0;
  int t = threadIdx.x, wid = t >> 6, lane = t & 63;

  for (int base = f0; base < f1; base += BATCH) {
    int nb = min(BATCH, f1 - base);
    __syncthreads();   // protect smask/slist reuse across batches
    // ---- phase 1: bbox test one face per thread, compact (order-preserving) ----
    bool keep = false;
    if (t < nb) {
      float4 b = *(const float4*)(frec + (size_t)(base + t)*20);
      // NaN-safe: NaN bbox -> reject==false -> keep (full test decides)
      keep = !(b.y < tpx0 || b.x > tpx1 || b.w < tpy0 || b.z > tpy1);
    }
    unsigned long long m = __ballot(keep);
    if (lane == 0) smask[wid] = m;
    __syncthreads();
    if (keep) {
      int pos = __popcll(m & ((1ull << lane) - 1ull));
      for (int w = 0; w < wid; ++w) pos += (int)__popcll(smask[w]);
      slist[pos] = base + t;
    }
    if (t == 0)
      s_ns = (int)(__popcll(smask[0]) + __popcll(smask[1]) +
                   __popcll(smask[2]) + __popcll(smask[3]));
    __syncthreads();
    int ns = s_ns;
    if (ns == 0) continue;

    // ---- phase 2: survivor loop, software-pipelined record loads ----
    int jc = slist[0];
    const float4* rp = (const float4*)(frec + (size_t)jc*20);
    float4 A1 = rp[1], A2 = rp[2], A3 = rp[3], A4 = rp[4];
    for (int k = 0; k < ns; ++k) {
      int jn = (k+1 < ns) ? slist[k+1] : jc;
      const float4* rq = (const float4*)(frec + (size_t)jn*20);
      float4 B1 = rq[1], B2 = rq[2], B3 = rq[3], B4 = rq[4];

      float x0=A1.x, y0=A1.y, x1=A1.z, y1=A1.w;
      float x2=A2.x, y2=A2.y, z0=A2.z, z1=A2.w;
      float z2=A3.x, e0x=A3.y, e0y=A3.z, e1x=A3.w;
      float e1y=A4.x, e2x=A4.y, e2y=A4.z;
      // w = ex*(py-ay) - ey*(px-ax), strict per-op rounding (no FMA)
      float w0 = __fsub_rn(__fmul_rn(e0x,__fsub_rn(py,y1)), __fmul_rn(e0y,__fsub_rn(px,x1)));
      float w1 = __fsub_rn(__fmul_rn(e1x,__fsub_rn(py,y2)), __fmul_rn(e1y,__fsub_rn(px,x2)));
      float w2 = __fsub_rn(__fmul_rn(e2x,__fsub_rn(py,y0)), __fmul_rn(e2y,__fsub_rn(px,x0)));
      float area = __fadd_rn(__fadd_rn(w0,w1),w2);
      bool sgn = (w0>=0.0f && w1>=0.0f && w2>=0.0f) || (w0<=0.0f && w1<=0.0f && w2<=0.0f);
      bool okf = fabsf(area) > 1e-10f;
      if (sgn && okf) {
        float inv = __fdiv_rn(1.0f, area);
        float q0 = __fdiv_rn(__fmul_rn(w0,inv), z0);
        float q1 = __fdiv_rn(__fmul_rn(w1,inv), z1);
        float q2 = __fdiv_rn(__fmul_rn(w2,inv), z2);
        float den = __fadd_rn(__fadd_rn(__fadd_rn(q0,q1),q2), 1e-12f);
        float zp = __fdiv_rn(1.0f, den);
        if (zp > 0.1f && zp < 100.0f && zp < bestd) { bestd = zp; besti = jc; }
      }
      A1=B1; A2=B2; A3=B3; A4=B4; jc=jn;
    }
  }
  int pix = y*SIMG + x;
  pd[(size_t)chunk*NPIX + pix] = bestd;
  pi[(size_t)chunk*NPIX + pix] = besti;
}

// grid 64 x 256: combine chunks (face order -> argmin first-index semantics),
// recompute winner color (exact ref sequence), write rgb+gray, block max ->
// atomicMax, last block computes the loss.  (Validated absmax=0 in R3.)
__global__ void __launch_bounds__(256) k_resolve_loss(
    const float* __restrict__ pd, const int* __restrict__ pi,
    const float* __restrict__ verts, const int* __restrict__ faces,
    const float* __restrict__ tex,
    const float* __restrict__ ldir, const float* __restrict__ idir,
    const float* __restrict__ iamb,
    const float* __restrict__ mimg, const float* __restrict__ mask,
    float* __restrict__ out_rgb, float* __restrict__ gray,
    int* __restrict__ counter, int* __restrict__ gmax_i,
    float* __restrict__ out, int nchunk)
{
  int pix = blockIdx.x*blockDim.x + threadIdx.x;
  float bestd = __builtin_inff();
  int   besti = 0;
  for (int c = 0; c < nchunk; ++c) {
    float d = pd[(size_t)c*NPIX + pix];
    int   i = pi[(size_t)c*NPIX + pix];
    if (d < bestd) { bestd = d; besti = i; }
  }
  bool hit = bestd < 1e30f;
  float c0=0.0f, c1=0.0f, c2=0.0f;
  if (hit) {
    int w = besti;
    int i0 = faces[3*w+0], i1 = faces[3*w+1], i2 = faces[3*w+2];
    float p0x=verts[3*i0+0], p0y=verts[3*i0+1], p0z=verts[3*i0+2];
    float p1x=verts[3*i1+0], p1y=verts[3*i1+1], p1z=verts[3*i1+2];
    float p2x=verts[3*i2+0], p2y=verts[3*i2+1], p2z=verts[3*i2+2];
    float ax=__fsub_rn(p0x,p1x), ay=__fsub_rn(p0y,p1y), az=__fsub_rn(p0z,p1z);
    float bx=__fsub_rn(p2x,p1x), by=__fsub_rn(p2y,p1y), bz=__fsub_rn(p2z,p1z);
    float nx=__fsub_rn(__fmul_rn(ay,bz),__fmul_rn(az,by));
    float ny=__fsub_rn(__fmul_rn(az,bx),__fmul_rn(ax,bz));
    float nz=__fsub_rn(__fmul_rn(ax,by),__fmul_rn(ay,bx));
    float nn=__fsqrt_rn(dot3_rn(nx,ny,nz,nx,ny,nz));
    nn = fmaxf(nn, 1e-5f);
    nx=__fdiv_rn(nx,nn); ny=__fdiv_rn(ny,nn); nz=__fdiv_rn(nz,nn);
    float cosv = fmaxf(0.0f, dot3_rn(nx,ny,nz, ldir[0],ldir[1],ldir[2]));
    float light = __fadd_rn(iamb[0], __fmul_rn(idir[0], cosv));
    c0 = __fmul_rn(tex[3*w+0], light);
    c1 = __fmul_rn(tex[3*w+1], light);
    c2 = __fmul_rn(tex[3*w+2], light);
  }
  out_rgb[pix]          = c0;
  out_rgb[NPIX + pix]   = c1;
  out_rgb[2*NPIX + pix] = c2;
  float g = __fadd_rn(__fadd_rn(c0,c1),c2);
  __hip_atomic_store(&gray[pix], g, __ATOMIC_RELAXED, __HIP_MEMORY_SCOPE_AGENT);

  float m = g;
  #pragma unroll
  for (int off = 32; off > 0; off >>= 1) m = fmaxf(m, __shfl_down(m, off, 64));
  __shared__ float sm[4];
  if ((threadIdx.x & 63) == 0) sm[threadIdx.x >> 6] = m;
  __syncthreads();
  if (threadIdx.x == 0) {
    m = fmaxf(fmaxf(sm[0],sm[1]), fmaxf(sm[2],sm[3]));
    atomicMax(gmax_i, __float_as_int(m));
  }

  __shared__ int is_last;
  __threadfence();
  if (threadIdx.x == 0) {
    int p = atomicAdd(counter, 1);
    is_last = (p == (int)gridDim.x - 1);
  }
  __syncthreads();
  if (!is_last) return;
  __threadfence();

  float mx = __int_as_float(__hip_atomic_load(gmax_i, __ATOMIC_RELAXED, __HIP_MEMORY_SCOPE_AGENT));
  float ssum = 0.0f, msum = 0.0f;
  for (int j = 0; j < NPIX/256; ++j) {
    int p2 = j*256 + threadIdx.x;
    float gv = __hip_atomic_load(&gray[p2], __ATOMIC_RELAXED, __HIP_MEMORY_SCOPE_AGENT);
    float gg = __fdiv_rn(gv, mx);
    float d  = __fsub_rn(gg, mimg[p2]);
    ssum = __fadd_rn(ssum, __fmul_rn(d,d));
    msum = __fadd_rn(msum, mask[p2]);
  }
  #pragma unroll
  for (int off = 32; off > 0; off >>= 1) {
    ssum += __shfl_down(ssum, off, 64);
    msum += __shfl_down(msum, off, 64);
  }
  __shared__ float s1[4], s2[4];
  if ((threadIdx.x & 63) == 0) { s1[threadIdx.x>>6] = ssum; s2[threadIdx.x>>6] = msum; }
  __syncthreads();
  if (threadIdx.x == 0) {
    ssum = ((s1[0]+s1[1])+(s1[2]+s1[3]));
    msum = ((s2[0]+s2[1])+(s2[2]+s2[3]));
    out[0] = __fdiv_rn(ssum, msum);
  }
}

extern "C" void kernel_launch(void* const* d_in, const int* in_sizes, int n_in,
                              void* d_out, int out_size, void* d_ws, size_t ws_size,
                              hipStream_t stream)
{
  const float* verts = (const float*)d_in[0];
  const int*   faces = (const int*)  d_in[1];
  const float* tex   = (const float*)d_in[2];
  const float* Rm    = (const float*)d_in[3];
  const float* tv    = (const float*)d_in[4];
  const float* Km    = (const float*)d_in[5];
  const float* mimg  = (const float*)d_in[6];
  const float* mask  = (const float*)d_in[7];
  const float* ldir  = (const float*)d_in[8];
  const float* idir  = (const float*)d_in[9];
  const float* iamb  = (const float*)d_in[10];
  int F = in_sizes[1] / 3;

  // ws (floats): frec F*20 | gray NPIX | gmax,counter(+pad 64) | pd nchunk*NPIX | pi nchunk*NPIX
  size_t fixed_floats = (size_t)F*20 + NPIX + 64;
  size_t avail_floats = ws_size / 4;
  int nchunk = 1;
  if (avail_floats > fixed_floats) {
    size_t per_chunk = (size_t)NPIX * 2;
    size_t c = (avail_floats - fixed_floats) / per_chunk;
    nchunk = (int)(c < 1 ? 1 : (c > MAXCHUNK ? MAXCHUNK : c));
  }
  int CF = (F + nchunk - 1) / nchunk;

  float* ws      = (float*)d_ws;
  float* frec    = ws;                                  // F*20
  float* gray    = frec + (size_t)F*20;                 // NPIX
  int*   gmax_i  = (int*)(gray + NPIX);                 // 1
  int*   counter = gmax_i + 1;                          // 1 (+62 pad)
  float* pd      = gray + NPIX + 64;                    // nchunk*NPIX
  int*   pi      = (int*)(pd + (size_t)nchunk*NPIX);    // nchunk*NPIX
  float* out     = (float*)d_out;

  hipLaunchKernelGGL(k_setup, dim3((F+255)/256), dim3(256), 0, stream,
                     verts, faces, Rm, tv, Km, frec, counter, gmax_i, F);
  hipLaunchKernelGGL(k_raster, dim3(64, nchunk), dim3(256), 0, stream,
                     frec, pd, pi, F, CF);
  hipLaunchKernelGGL(k_resolve_loss, dim3(64), dim3(256), 0, stream,
                     pd, pi, verts, faces, tex, ldir, idir, iamb, mimg, mask,
                     out + 1, gray, counter, gmax_i, out, nchunk);
}

// Round 5
// 109.572 us; speedup vs baseline: 1.4364x; 1.3951x over previous
//
#include <hip/hip_runtime.h>
#include <math.h>

#define SIMG 128
#define NPIX (SIMG*SIMG)

// ((a0*b0 + a1*b1) + a2*b2) with strict per-op fp32 rounding (matches numpy einsum order)
__device__ __forceinline__ float dot3_rn(float a0,float a1,float a2,float b0,float b1,float b2){
  return __fadd_rn(__fadd_rn(__fmul_rn(a0,b0),__fmul_rn(a1,b1)),__fmul_rn(a2,b2));
}

// One wave per face: compute face record in registers (all 64 lanes redundantly,
// broadcast loads), walk the face's pixel bbox 64 px at a time, commit via
// atomicMin on packed (depth_bits<<32)|face_idx. depth>0.1 -> int-monotone;
// equal depth -> smaller face idx wins = np.argmin first-occurrence semantics.
__global__ void __launch_bounds__(256) k_raster_face(
    const float* __restrict__ verts, const int* __restrict__ faces,
    const float* __restrict__ Rm, const float* __restrict__ tv,
    const float* __restrict__ Km,
    unsigned long long* __restrict__ zbuf, int F)
{
  int f = (int)((blockIdx.x*blockDim.x + threadIdx.x) >> 6);
  if (f >= F) return;
  int lane = threadIdx.x & 63;

  // ---- face record (exact reference op sequence — validated absmax=0 R2-R4) ----
  float uu[3], vv2[3], zz[3];
  #pragma unroll
  for (int k=0;k<3;k++){
    int vi = faces[3*f+k];
    float X = verts[3*vi+0], Y = verts[3*vi+1], Z = verts[3*vi+2];
    float cx = __fadd_rn(dot3_rn(X,Y,Z, Rm[0],Rm[1],Rm[2]), tv[0]);
    float cy = __fadd_rn(dot3_rn(X,Y,Z, Rm[3],Rm[4],Rm[5]), tv[1]);
    float cz = __fadd_rn(dot3_rn(X,Y,Z, Rm[6],Rm[7],Rm[8]), tv[2]);
    float zd = __fadd_rn(cz, 1e-9f);
    float x_ = __fdiv_rn(cx, zd);
    float y_ = __fdiv_rn(cy, zd);
    float ur = __fadd_rn(__fadd_rn(__fmul_rn(x_,Km[0]),__fmul_rn(y_,Km[1])), Km[2]);
    float vr = __fadd_rn(__fadd_rn(__fmul_rn(x_,Km[3]),__fmul_rn(y_,Km[4])), Km[5]);
    float vflip = __fsub_rn(128.0f, vr);
    uu[k]  = __fdiv_rn(__fmul_rn(2.0f, __fsub_rn(ur,   64.0f)), 128.0f);
    vv2[k] = __fdiv_rn(__fmul_rn(2.0f, __fsub_rn(vflip,64.0f)), 128.0f);
    zz[k]  = cz;
  }
  float x0=uu[0], y0=vv2[0], x1=uu[1], y1=vv2[1], x2=uu[2], y2=vv2[2];
  float z0=zz[0], z1=zz[1], z2=zz[2];
  float e0x=__fsub_rn(x2,x1), e0y=__fsub_rn(y2,y1);
  float e1x=__fsub_rn(x0,x2), e1y=__fsub_rn(y0,y2);
  float e2x=__fsub_rn(x1,x0), e2y=__fsub_rn(y1,y0);
  float bxmin = fminf(fminf(x0,x1),x2) - 1e-4f;
  float bxmax = fmaxf(fmaxf(x0,x1),x2) + 1e-4f;
  float bymin = fminf(fminf(y0,y1),y2) - 1e-4f;
  float bymax = fmaxf(fmaxf(y0,y1),y2) + 1e-4f;

  // NDC bbox -> pixel index range: px(x) = (2x+1-128)/128, so x s.t. px in bbox.
  // +-1 px margin absorbs conversion rounding; margin pixels are outside the
  // slop-bbox => outside triangle => sign test rejects (fp error << 1e-4 slop).
  int x0p = (int)ceilf(__fmaf_rn(64.0f, bxmin, 63.5f)) - 1;
  int x1p = (int)floorf(__fmaf_rn(64.0f, bxmax, 63.5f)) + 1;
  int y0p = (int)ceilf(__fmaf_rn(64.0f, bymin, 63.5f)) - 1;
  int y1p = (int)floorf(__fmaf_rn(64.0f, bymax, 63.5f)) + 1;
  x0p = max(x0p, 0); y0p = max(y0p, 0);
  x1p = min(x1p, SIMG-1); y1p = min(y1p, SIMG-1);
  int W = x1p - x0p + 1, H = y1p - y0p + 1;
  if (W <= 0 || H <= 0) return;
  int shift = (W <= 1) ? 0 : (32 - __clz(W - 1));   // pow2 pad: x from mask, y from shift
  int W2 = 1 << shift;
  int total = W2 * H;

  for (int i = lane; i < total; i += 64) {
    int xx = x0p + (i & (W2 - 1));
    int yy = y0p + (i >> shift);
    if (xx > x1p) continue;               // pad lanes (also keeps xx < SIMG)
    float px = (float)(2*xx + 1 - SIMG) / 128.0f;   // exact
    float py = (float)(2*yy + 1 - SIMG) / 128.0f;   // exact
    // w = ex*(py-ay) - ey*(px-ax), strict per-op rounding (no FMA)
    float w0 = __fsub_rn(__fmul_rn(e0x,__fsub_rn(py,y1)), __fmul_rn(e0y,__fsub_rn(px,x1)));
    float w1 = __fsub_rn(__fmul_rn(e1x,__fsub_rn(py,y2)), __fmul_rn(e1y,__fsub_rn(px,x2)));
    float w2 = __fsub_rn(__fmul_rn(e2x,__fsub_rn(py,y0)), __fmul_rn(e2y,__fsub_rn(px,x0)));
    float area = __fadd_rn(__fadd_rn(w0,w1),w2);
    bool sgn = (w0>=0.0f && w1>=0.0f && w2>=0.0f) || (w0<=0.0f && w1<=0.0f && w2<=0.0f);
    bool okf = fabsf(area) > 1e-10f;
    if (sgn && okf) {
      float inv = __fdiv_rn(1.0f, area);
      float q0 = __fdiv_rn(__fmul_rn(w0,inv), z0);
      float q1 = __fdiv_rn(__fmul_rn(w1,inv), z1);
      float q2 = __fdiv_rn(__fmul_rn(w2,inv), z2);
      float den = __fadd_rn(__fadd_rn(__fadd_rn(q0,q1),q2), 1e-12f);
      float zp = __fdiv_rn(1.0f, den);
      if (zp > 0.1f && zp < 100.0f) {
        unsigned long long pack =
            ((unsigned long long)(unsigned int)__float_as_int(zp) << 32) |
            (unsigned int)f;
        atomicMin(&zbuf[yy*SIMG + xx], pack);
      }
    }
  }
}

// grid 64 x 256: read packed zbuf, recompute winner color (exact ref sequence),
// write rgb+gray, block max -> atomicMax, last block computes the loss.
// (Fused-reduction structure validated absmax=0 in R3/R4.)
__global__ void __launch_bounds__(256) k_resolve_loss(
    const unsigned long long* __restrict__ zbuf,
    const float* __restrict__ verts, const int* __restrict__ faces,
    const float* __restrict__ tex,
    const float* __restrict__ ldir, const float* __restrict__ idir,
    const float* __restrict__ iamb,
    const float* __restrict__ mimg, const float* __restrict__ mask,
    float* __restrict__ out_rgb, float* __restrict__ gray,
    int* __restrict__ counter, int* __restrict__ gmax_i,
    float* __restrict__ out)
{
  int pix = blockIdx.x*blockDim.x + threadIdx.x;
  unsigned long long v = zbuf[pix];
  bool hit = (unsigned int)(v >> 32) < 0x7f800000u;   // finite depth recorded
  float c0=0.0f, c1=0.0f, c2=0.0f;
  if (hit) {
    int w = (int)(v & 0xffffffffu);
    int i0 = faces[3*w+0], i1 = faces[3*w+1], i2 = faces[3*w+2];
    float p0x=verts[3*i0+0], p0y=verts[3*i0+1], p0z=verts[3*i0+2];
    float p1x=verts[3*i1+0], p1y=verts[3*i1+1], p1z=verts[3*i1+2];
    float p2x=verts[3*i2+0], p2y=verts[3*i2+1], p2z=verts[3*i2+2];
    float ax=__fsub_rn(p0x,p1x), ay=__fsub_rn(p0y,p1y), az=__fsub_rn(p0z,p1z);
    float bx=__fsub_rn(p2x,p1x), by=__fsub_rn(p2y,p1y), bz=__fsub_rn(p2z,p1z);
    float nx=__fsub_rn(__fmul_rn(ay,bz),__fmul_rn(az,by));
    float ny=__fsub_rn(__fmul_rn(az,bx),__fmul_rn(ax,bz));
    float nz=__fsub_rn(__fmul_rn(ax,by),__fmul_rn(ay,bx));
    float nn=__fsqrt_rn(dot3_rn(nx,ny,nz,nx,ny,nz));
    nn = fmaxf(nn, 1e-5f);
    nx=__fdiv_rn(nx,nn); ny=__fdiv_rn(ny,nn); nz=__fdiv_rn(nz,nn);
    float cosv = fmaxf(0.0f, dot3_rn(nx,ny,nz, ldir[0],ldir[1],ldir[2]));
    float light = __fadd_rn(iamb[0], __fmul_rn(idir[0], cosv));
    c0 = __fmul_rn(tex[3*w+0], light);
    c1 = __fmul_rn(tex[3*w+1], light);
    c2 = __fmul_rn(tex[3*w+2], light);
  }
  out_rgb[pix]          = c0;
  out_rgb[NPIX + pix]   = c1;
  out_rgb[2*NPIX + pix] = c2;
  float g = __fadd_rn(__fadd_rn(c0,c1),c2);
  __hip_atomic_store(&gray[pix], g, __ATOMIC_RELAXED, __HIP_MEMORY_SCOPE_AGENT);

  float m = g;
  #pragma unroll
  for (int off = 32; off > 0; off >>= 1) m = fmaxf(m, __shfl_down(m, off, 64));
  __shared__ float sm[4];
  if ((threadIdx.x & 63) == 0) sm[threadIdx.x >> 6] = m;
  __syncthreads();
  if (threadIdx.x == 0) {
    m = fmaxf(fmaxf(sm[0],sm[1]), fmaxf(sm[2],sm[3]));
    atomicMax(gmax_i, __float_as_int(m));   // init 0; gray >= 0 so int cmp is monotone
  }

  __shared__ int is_last;
  __threadfence();
  if (threadIdx.x == 0) {
    int p = atomicAdd(counter, 1);
    is_last = (p == (int)gridDim.x - 1);
  }
  __syncthreads();
  if (!is_last) return;
  __threadfence();

  float mx = __int_as_float(__hip_atomic_load(gmax_i, __ATOMIC_RELAXED, __HIP_MEMORY_SCOPE_AGENT));
  float ssum = 0.0f, msum = 0.0f;
  for (int j = 0; j < NPIX/256; ++j) {
    int p2 = j*256 + threadIdx.x;
    float gv = __hip_atomic_load(&gray[p2], __ATOMIC_RELAXED, __HIP_MEMORY_SCOPE_AGENT);
    float gg = __fdiv_rn(gv, mx);
    float d  = __fsub_rn(gg, mimg[p2]);
    ssum = __fadd_rn(ssum, __fmul_rn(d,d));
    msum = __fadd_rn(msum, mask[p2]);
  }
  #pragma unroll
  for (int off = 32; off > 0; off >>= 1) {
    ssum += __shfl_down(ssum, off, 64);
    msum += __shfl_down(msum, off, 64);
  }
  __shared__ float s1[4], s2[4];
  if ((threadIdx.x & 63) == 0) { s1[threadIdx.x>>6] = ssum; s2[threadIdx.x>>6] = msum; }
  __syncthreads();
  if (threadIdx.x == 0) {
    ssum = ((s1[0]+s1[1])+(s1[2]+s1[3]));
    msum = ((s2[0]+s2[1])+(s2[2]+s2[3]));
    out[0] = __fdiv_rn(ssum, msum);
  }
}

extern "C" void kernel_launch(void* const* d_in, const int* in_sizes, int n_in,
                              void* d_out, int out_size, void* d_ws, size_t ws_size,
                              hipStream_t stream)
{
  const float* verts = (const float*)d_in[0];
  const int*   faces = (const int*)  d_in[1];
  const float* tex   = (const float*)d_in[2];
  const float* Rm    = (const float*)d_in[3];
  const float* tv    = (const float*)d_in[4];
  const float* Km    = (const float*)d_in[5];
  const float* mimg  = (const float*)d_in[6];
  const float* mask  = (const float*)d_in[7];
  const float* ldir  = (const float*)d_in[8];
  const float* idir  = (const float*)d_in[9];
  const float* iamb  = (const float*)d_in[10];
  int F = in_sizes[1] / 3;

  // ws: zbuf NPIX u64 (128 KB) | gray NPIX f32 | gmax,counter
  unsigned long long* zbuf = (unsigned long long*)d_ws;
  float* gray    = (float*)(zbuf + NPIX);
  int*   gmax_i  = (int*)(gray + NPIX);
  int*   counter = gmax_i + 1;
  float* out     = (float*)d_out;

  // sentinel: 0xFF..FF > any packed (depth in (0.1,100) has positive-finite bits)
  hipMemsetAsync(zbuf, 0xFF, (size_t)NPIX*sizeof(unsigned long long), stream);
  hipMemsetAsync(gmax_i, 0, 2*sizeof(int), stream);   // gmax=0.0f bits, counter=0

  hipLaunchKernelGGL(k_raster_face, dim3((F + 3)/4), dim3(256), 0, stream,
                     verts, faces, Rm, tv, Km, zbuf, F);
  hipLaunchKernelGGL(k_resolve_loss, dim3(64), dim3(256), 0, stream,
                     zbuf, verts, faces, tex, ldir, idir, iamb, mimg, mask,
                     out + 1, gray, counter, gmax_i, out);
}